// Round 1
// baseline (2562.837 us; speedup 1.0000x reference)
//
#include <hip/hip_runtime.h>
#include <math.h>

#define FDIM 256
#define NGRAPH 128
#define NCLASS 10

// ---------------- degree / norm precompute ----------------

__global__ void deg_kernel(const int* __restrict__ dst, float* __restrict__ deg, int E) {
    int e = blockIdx.x * blockDim.x + threadIdx.x;
    if (e < E) atomicAdd(&deg[dst[e]], 1.0f);
}

__global__ void dinv_kernel(const float* __restrict__ deg, float* __restrict__ dinv, int N) {
    int i = blockIdx.x * blockDim.x + threadIdx.x;
    if (i < N) dinv[i] = rsqrtf(deg[i] + 1.0f);   // +1 = self loop; always > 0
}

__global__ void norm_kernel(const int* __restrict__ src, const int* __restrict__ dst,
                            const float* __restrict__ dinv, float* __restrict__ norm, int E) {
    int e = blockIdx.x * blockDim.x + threadIdx.x;
    if (e < E) norm[e] = dinv[src[e]] * dinv[dst[e]];
}

// ---------------- tiled fp32 SGEMM: C[M,256] = A[M,256] @ B[256,256] ----------------
// BM=64, BN=64, BK=16, 256 threads, 4x4 micro-tile per thread.

__global__ __launch_bounds__(256) void sgemm_kernel(const float* __restrict__ A,
                                                    const float* __restrict__ B,
                                                    float* __restrict__ C, int M) {
    __shared__ float As[16][65];   // [k][m], +1 pad
    __shared__ float Bs[16][64];   // [k][n]
    const int bm = blockIdx.x * 64;
    const int bn = blockIdx.y * 64;
    const int t  = threadIdx.x;
    const int tx = t & 15;         // n-quad
    const int ty = t >> 4;         // m-quad
    const int la_k = t & 15;       // A-load: k
    const int la_m = t >> 4;       // A-load: base row (16 rows/iter)
    const int lb_n = t & 63;       // B-load: n
    const int lb_k = t >> 6;       // B-load: base k (4 k/iter)

    float acc[4][4] = {};

    for (int k0 = 0; k0 < 256; k0 += 16) {
#pragma unroll
        for (int i = 0; i < 4; i++) {
            int m = la_m + i * 16;
            int row = bm + m;
            As[la_k][m] = (row < M) ? A[(size_t)row * FDIM + k0 + la_k] : 0.0f;
        }
#pragma unroll
        for (int i = 0; i < 4; i++) {
            int k = lb_k + i * 4;
            Bs[k][lb_n] = B[(size_t)(k0 + k) * FDIM + bn + lb_n];
        }
        __syncthreads();
#pragma unroll
        for (int k = 0; k < 16; k++) {
            float a[4], b[4];
#pragma unroll
            for (int i = 0; i < 4; i++) a[i] = As[k][ty * 4 + i];
#pragma unroll
            for (int j = 0; j < 4; j++) b[j] = Bs[k][tx * 4 + j];
#pragma unroll
            for (int i = 0; i < 4; i++)
#pragma unroll
                for (int j = 0; j < 4; j++) acc[i][j] += a[i] * b[j];
        }
        __syncthreads();
    }
#pragma unroll
    for (int i = 0; i < 4; i++) {
        int row = bm + ty * 4 + i;
        if (row < M) {
#pragma unroll
            for (int j = 0; j < 4; j++)
                C[(size_t)row * FDIM + bn + tx * 4 + j] = acc[i][j];
        }
    }
}

// ---------------- edge scatter (atomic) ----------------
// one block per edge; thread = feature

__global__ __launch_bounds__(256) void scatter_kernel(const float* __restrict__ h,
                                                      const int* __restrict__ src,
                                                      const int* __restrict__ dst,
                                                      const float* __restrict__ norm,
                                                      float* __restrict__ out, int E) {
    int e = blockIdx.x;
    int f = threadIdx.x;
    int s = src[e], d = dst[e];
    float v = h[(size_t)s * FDIM + f] * norm[e];
    atomicAdd(&out[(size_t)d * FDIM + f], v);
}

// ---------------- self-loop + bias + relu (in place on agg) ----------------

__global__ __launch_bounds__(256) void biasrelu_kernel(float* __restrict__ agg,
                                                       const float* __restrict__ h,
                                                       const float* __restrict__ dinv,
                                                       const float* __restrict__ bias, int N) {
    int i = blockIdx.x;
    int f = threadIdx.x;
    float di = dinv[i];
    size_t idx = (size_t)i * FDIM + f;
    float v = agg[idx] + di * di * h[idx] + bias[f];
    agg[idx] = fmaxf(v, 0.0f);
}

// ---------------- global add pool (batch is sorted; run-length compress atomics) ----------------

__global__ __launch_bounds__(256) void pool_kernel(const float* __restrict__ state,
                                                   const int* __restrict__ batch,
                                                   float* __restrict__ g, int N) {
    int n0 = blockIdx.x * 16;
    int f = threadIdx.x;
    int cur = -1;
    float run = 0.0f;
    for (int i = 0; i < 16; i++) {
        int n = n0 + i;
        if (n >= N) break;
        int b = batch[n];
        if (b != cur) {
            if (cur >= 0) atomicAdd(&g[(size_t)cur * FDIM + f], run);
            cur = b;
            run = 0.0f;
        }
        run += state[(size_t)n * FDIM + f];
    }
    if (cur >= 0) atomicAdd(&g[(size_t)cur * FDIM + f], run);
}

// ---------------- FC1 + relu ----------------

__global__ __launch_bounds__(256) void fc1_kernel(const float* __restrict__ g,
                                                  const float* __restrict__ W,
                                                  const float* __restrict__ b,
                                                  float* __restrict__ out) {
    __shared__ float gs[FDIM];
    int r = blockIdx.x, f = threadIdx.x;
    gs[f] = g[(size_t)r * FDIM + f];
    __syncthreads();
    float acc = b[f];
    for (int k = 0; k < FDIM; k++) acc += gs[k] * W[(size_t)k * FDIM + f];
    out[(size_t)r * FDIM + f] = fmaxf(acc, 0.0f);
}

// ---------------- FC2 + log_softmax ----------------

__global__ __launch_bounds__(64) void fc2_kernel(const float* __restrict__ gh,
                                                 const float* __restrict__ W,
                                                 const float* __restrict__ b,
                                                 float* __restrict__ out) {
    __shared__ float gs[FDIM];
    __shared__ float logits[NCLASS];
    int r = blockIdx.x;
    int t = threadIdx.x;
    for (int k = t; k < FDIM; k += 64) gs[k] = gh[(size_t)r * FDIM + k];
    __syncthreads();
    if (t < NCLASS) {
        float acc = b[t];
        for (int k = 0; k < FDIM; k++) acc += gs[k] * W[(size_t)k * NCLASS + t];
        logits[t] = acc;
    }
    __syncthreads();
    if (t == 0) {
        float mx = logits[0];
        for (int c = 1; c < NCLASS; c++) mx = fmaxf(mx, logits[c]);
        float s = 0.0f;
        for (int c = 0; c < NCLASS; c++) s += expf(logits[c] - mx);
        float lse = mx + logf(s);
        for (int c = 0; c < NCLASS; c++) out[(size_t)r * NCLASS + c] = logits[c] - lse;
    }
}

// ---------------- launcher ----------------

extern "C" void kernel_launch(void* const* d_in, const int* in_sizes, int n_in,
                              void* d_out, int out_size, void* d_ws, size_t ws_size,
                              hipStream_t stream) {
    const float* x     = (const float*)d_in[0];
    const int*   ei    = (const int*)d_in[1];    // [2][E]: row0 src, row1 dst
    const int*   batch = (const int*)d_in[2];
    const float* W0 = (const float*)d_in[3];  const float* b0 = (const float*)d_in[4];
    const float* W1 = (const float*)d_in[5];  const float* b1 = (const float*)d_in[6];
    const float* W2 = (const float*)d_in[7];  const float* b2 = (const float*)d_in[8];
    const float* fc1W = (const float*)d_in[9];  const float* fc1b = (const float*)d_in[10];
    const float* fc2W = (const float*)d_in[11]; const float* fc2b = (const float*)d_in[12];
    float* out = (float*)d_out;

    const int N = in_sizes[0] / FDIM;
    const int E = in_sizes[1] / 2;
    const int* src = ei;
    const int* dst = ei + E;

    // workspace layout (floats)
    float* ws   = (float*)d_ws;
    float* B1   = ws;                          // N*256  (GEMM output h)
    float* B2   = B1 + (size_t)N * FDIM;       // N*256  (aggregate / node state)
    float* dinv = B2 + (size_t)N * FDIM;       // N
    float* deg  = dinv + N;                    // N
    float* norm = deg + N;                     // E
    float* g    = norm + E;                    // 128*256
    float* gh   = g + (size_t)NGRAPH * FDIM;   // 128*256

    // degree + norm (recomputed every launch; inputs restored by harness)
    hipMemsetAsync(deg, 0, (size_t)N * sizeof(float), stream);
    deg_kernel<<<(E + 255) / 256, 256, 0, stream>>>(dst, deg, E);
    dinv_kernel<<<(N + 255) / 256, 256, 0, stream>>>(deg, dinv, N);
    norm_kernel<<<(E + 255) / 256, 256, 0, stream>>>(src, dst, dinv, norm, E);

    const float* Ws[3] = {W0, W1, W2};
    const float* bs[3] = {b0, b1, b2};
    const float* xin = x;
    dim3 ggrid((N + 63) / 64, 4);
    for (int l = 0; l < 3; l++) {
        sgemm_kernel<<<ggrid, 256, 0, stream>>>(xin, Ws[l], B1, N);
        hipMemsetAsync(B2, 0, (size_t)N * FDIM * sizeof(float), stream);
        scatter_kernel<<<E, 256, 0, stream>>>(B1, src, dst, norm, B2, E);
        biasrelu_kernel<<<N, 256, 0, stream>>>(B2, B1, dinv, bs[l], N);
        xin = B2;
    }

    hipMemsetAsync(g, 0, (size_t)NGRAPH * FDIM * sizeof(float), stream);
    pool_kernel<<<(N + 15) / 16, 256, 0, stream>>>(B2, batch, g, N);
    fc1_kernel<<<NGRAPH, 256, 0, stream>>>(g, fc1W, fc1b, gh);
    fc2_kernel<<<NGRAPH, 64, 0, stream>>>(gh, fc2W, fc2b, out);
}

// Round 2
// 968.042 us; speedup vs baseline: 2.6474x; 2.6474x over previous
//
#include <hip/hip_runtime.h>
#include <math.h>

#define FDIM 256
#define NGRAPH 128
#define NCLASS 10

// ---------------- CSR build: count / dinv / scan / fill ----------------

__global__ void count_kernel(const int* __restrict__ dst, int* __restrict__ cnt, int E) {
    int e = blockIdx.x * blockDim.x + threadIdx.x;
    if (e < E) atomicAdd(&cnt[dst[e]], 1);
}

__global__ void dinv_kernel(const int* __restrict__ cnt, float* __restrict__ dinv, int N) {
    int i = blockIdx.x * blockDim.x + threadIdx.x;
    if (i < N) dinv[i] = rsqrtf((float)cnt[i] + 1.0f);   // +1 = self loop; always > 0
}

// single-block exclusive scan of cnt[0..N) -> rowptr[0..N]
__global__ __launch_bounds__(1024) void scan_kernel(const int* __restrict__ cnt,
                                                    int* __restrict__ rowptr, int N, int E) {
    __shared__ int sums[1024];
    const int t = threadIdx.x;
    const int chunk = (N + 1023) / 1024;
    const int beg = t * chunk;
    const int end = min(beg + chunk, N);
    int s = 0;
    for (int i = beg; i < end; i++) s += cnt[i];
    sums[t] = s;
    __syncthreads();
    for (int off = 1; off < 1024; off <<= 1) {
        int v = (t >= off) ? sums[t - off] : 0;
        __syncthreads();
        sums[t] += v;
        __syncthreads();
    }
    int run = (t == 0) ? 0 : sums[t - 1];
    for (int i = beg; i < end; i++) { rowptr[i] = run; run += cnt[i]; }
    if (t == 1023) rowptr[N] = E;
}

__global__ void fill_kernel(const int* __restrict__ src, const int* __restrict__ dst,
                            const int* __restrict__ rowptr, int* __restrict__ cursor,
                            int* __restrict__ srcs, int E) {
    int e = blockIdx.x * blockDim.x + threadIdx.x;
    if (e < E) {
        int d = dst[e];
        int pos = atomicAdd(&cursor[d], 1);
        srcs[rowptr[d] + pos] = src[e];
    }
}

// ---------------- tiled fp32 SGEMM: C[M,256] = A[M,256] @ B[256,256] ----------------

__global__ __launch_bounds__(256) void sgemm_kernel(const float* __restrict__ A,
                                                    const float* __restrict__ B,
                                                    float* __restrict__ C, int M) {
    __shared__ float As[16][65];
    __shared__ float Bs[16][64];
    const int bm = blockIdx.x * 64;
    const int bn = blockIdx.y * 64;
    const int t  = threadIdx.x;
    const int tx = t & 15;
    const int ty = t >> 4;
    const int la_k = t & 15;
    const int la_m = t >> 4;
    const int lb_n = t & 63;
    const int lb_k = t >> 6;

    float acc[4][4] = {};

    for (int k0 = 0; k0 < 256; k0 += 16) {
#pragma unroll
        for (int i = 0; i < 4; i++) {
            int m = la_m + i * 16;
            int row = bm + m;
            As[la_k][m] = (row < M) ? A[(size_t)row * FDIM + k0 + la_k] : 0.0f;
        }
#pragma unroll
        for (int i = 0; i < 4; i++) {
            int k = lb_k + i * 4;
            Bs[k][lb_n] = B[(size_t)(k0 + k) * FDIM + bn + lb_n];
        }
        __syncthreads();
#pragma unroll
        for (int k = 0; k < 16; k++) {
            float a[4], b[4];
#pragma unroll
            for (int i = 0; i < 4; i++) a[i] = As[k][ty * 4 + i];
#pragma unroll
            for (int j = 0; j < 4; j++) b[j] = Bs[k][tx * 4 + j];
#pragma unroll
            for (int i = 0; i < 4; i++)
#pragma unroll
                for (int j = 0; j < 4; j++) acc[i][j] += a[i] * b[j];
        }
        __syncthreads();
    }
#pragma unroll
    for (int i = 0; i < 4; i++) {
        int row = bm + ty * 4 + i;
        if (row < M) {
#pragma unroll
            for (int j = 0; j < 4; j++)
                C[(size_t)row * FDIM + bn + tx * 4 + j] = acc[i][j];
        }
    }
}

// ---------------- fused gather + self-loop + bias + relu ----------------
// one wave per dst node; lane covers 4 consecutive floats (float4).

__global__ __launch_bounds__(256) void gather_kernel(const float4* __restrict__ h4,
                                                     const int* __restrict__ rowptr,
                                                     const int* __restrict__ srcs,
                                                     const float* __restrict__ dinv,
                                                     const float* __restrict__ bias,
                                                     float4* __restrict__ out4, int N) {
    const int node = blockIdx.x * 4 + (threadIdx.x >> 6);
    const int lane = threadIdx.x & 63;
    if (node >= N) return;
    const float di = dinv[node];
    float4 self = h4[(size_t)node * 64 + lane];
    float4 b = ((const float4*)bias)[lane];
    float4 acc;
    acc.x = di * di * self.x + b.x;
    acc.y = di * di * self.y + b.y;
    acc.z = di * di * self.z + b.z;
    acc.w = di * di * self.w + b.w;
    const int beg = rowptr[node];
    const int end = rowptr[node + 1];
    for (int p = beg; p < end; p++) {
        int s = srcs[p];
        float nm = dinv[s] * di;
        float4 v = h4[(size_t)s * 64 + lane];
        acc.x += v.x * nm;
        acc.y += v.y * nm;
        acc.z += v.z * nm;
        acc.w += v.w * nm;
    }
    acc.x = fmaxf(acc.x, 0.0f);
    acc.y = fmaxf(acc.y, 0.0f);
    acc.z = fmaxf(acc.z, 0.0f);
    acc.w = fmaxf(acc.w, 0.0f);
    out4[(size_t)node * 64 + lane] = acc;
}

// ---------------- global add pool (batch sorted; run-length compress atomics) ----------------

__global__ __launch_bounds__(256) void pool_kernel(const float* __restrict__ state,
                                                   const int* __restrict__ batch,
                                                   float* __restrict__ g, int N) {
    int n0 = blockIdx.x * 16;
    int f = threadIdx.x;
    int cur = -1;
    float run = 0.0f;
    for (int i = 0; i < 16; i++) {
        int n = n0 + i;
        if (n >= N) break;
        int b = batch[n];
        if (b != cur) {
            if (cur >= 0) atomicAdd(&g[(size_t)cur * FDIM + f], run);
            cur = b;
            run = 0.0f;
        }
        run += state[(size_t)n * FDIM + f];
    }
    if (cur >= 0) atomicAdd(&g[(size_t)cur * FDIM + f], run);
}

// ---------------- FC1 + relu ----------------

__global__ __launch_bounds__(256) void fc1_kernel(const float* __restrict__ g,
                                                  const float* __restrict__ W,
                                                  const float* __restrict__ b,
                                                  float* __restrict__ out) {
    __shared__ float gs[FDIM];
    int r = blockIdx.x, f = threadIdx.x;
    gs[f] = g[(size_t)r * FDIM + f];
    __syncthreads();
    float acc = b[f];
    for (int k = 0; k < FDIM; k++) acc += gs[k] * W[(size_t)k * FDIM + f];
    out[(size_t)r * FDIM + f] = fmaxf(acc, 0.0f);
}

// ---------------- FC2 + log_softmax ----------------

__global__ __launch_bounds__(64) void fc2_kernel(const float* __restrict__ gh,
                                                 const float* __restrict__ W,
                                                 const float* __restrict__ b,
                                                 float* __restrict__ out) {
    __shared__ float gs[FDIM];
    __shared__ float logits[NCLASS];
    int r = blockIdx.x;
    int t = threadIdx.x;
    for (int k = t; k < FDIM; k += 64) gs[k] = gh[(size_t)r * FDIM + k];
    __syncthreads();
    if (t < NCLASS) {
        float acc = b[t];
        for (int k = 0; k < FDIM; k++) acc += gs[k] * W[(size_t)k * NCLASS + t];
        logits[t] = acc;
    }
    __syncthreads();
    if (t == 0) {
        float mx = logits[0];
        for (int c = 1; c < NCLASS; c++) mx = fmaxf(mx, logits[c]);
        float s = 0.0f;
        for (int c = 0; c < NCLASS; c++) s += expf(logits[c] - mx);
        float lse = mx + logf(s);
        for (int c = 0; c < NCLASS; c++) out[(size_t)r * NCLASS + c] = logits[c] - lse;
    }
}

// ---------------- launcher ----------------

extern "C" void kernel_launch(void* const* d_in, const int* in_sizes, int n_in,
                              void* d_out, int out_size, void* d_ws, size_t ws_size,
                              hipStream_t stream) {
    const float* x     = (const float*)d_in[0];
    const int*   ei    = (const int*)d_in[1];
    const int*   batch = (const int*)d_in[2];
    const float* W0 = (const float*)d_in[3];  const float* b0 = (const float*)d_in[4];
    const float* W1 = (const float*)d_in[5];  const float* b1 = (const float*)d_in[6];
    const float* W2 = (const float*)d_in[7];  const float* b2 = (const float*)d_in[8];
    const float* fc1W = (const float*)d_in[9];  const float* fc1b = (const float*)d_in[10];
    const float* fc2W = (const float*)d_in[11]; const float* fc2b = (const float*)d_in[12];
    float* out = (float*)d_out;

    const int N = in_sizes[0] / FDIM;
    const int E = in_sizes[1] / 2;
    const int* src = ei;
    const int* dst = ei + E;

    // workspace layout
    float* ws   = (float*)d_ws;
    float* B1   = ws;                          // N*256  (GEMM output h)
    float* B2   = B1 + (size_t)N * FDIM;       // N*256  (node state)
    float* dinv = B2 + (size_t)N * FDIM;       // N
    int*   cnt  = (int*)(dinv + N);            // N (also reused as fill cursor)
    int*   rowptr = cnt + N;                   // N+1
    int*   srcs = rowptr + N + 1;              // E
    float* g    = (float*)(srcs + E);          // 128*256
    float* gh   = g + (size_t)NGRAPH * FDIM;   // 128*256

    // ---- CSR build (per launch; harness restores inputs each call) ----
    hipMemsetAsync(cnt, 0, (size_t)N * sizeof(int), stream);
    count_kernel<<<(E + 255) / 256, 256, 0, stream>>>(dst, cnt, E);
    dinv_kernel<<<(N + 255) / 256, 256, 0, stream>>>(cnt, dinv, N);
    scan_kernel<<<1, 1024, 0, stream>>>(cnt, rowptr, N, E);
    hipMemsetAsync(cnt, 0, (size_t)N * sizeof(int), stream);   // -> cursor
    fill_kernel<<<(E + 255) / 256, 256, 0, stream>>>(src, dst, rowptr, cnt, srcs, E);

    // ---- 3 GCN layers ----
    const float* Ws[3] = {W0, W1, W2};
    const float* bs[3] = {b0, b1, b2};
    const float* xin = x;
    dim3 ggrid((N + 63) / 64, 4);
    for (int l = 0; l < 3; l++) {
        sgemm_kernel<<<ggrid, 256, 0, stream>>>(xin, Ws[l], B1, N);
        gather_kernel<<<(N + 3) / 4, 256, 0, stream>>>((const float4*)B1, rowptr, srcs,
                                                       dinv, bs[l], (float4*)B2, N);
        xin = B2;
    }

    // ---- head ----
    hipMemsetAsync(g, 0, (size_t)NGRAPH * FDIM * sizeof(float), stream);
    pool_kernel<<<(N + 15) / 16, 256, 0, stream>>>(B2, batch, g, N);
    fc1_kernel<<<NGRAPH, 256, 0, stream>>>(g, fc1W, fc1b, gh);
    fc2_kernel<<<NGRAPH, 64, 0, stream>>>(gh, fc2W, fc2b, out);
}

// Round 3
// 640.447 us; speedup vs baseline: 4.0016x; 1.5115x over previous
//
#include <hip/hip_runtime.h>
#include <math.h>

#define FDIM 256
#define NGRAPH 128
#define NCLASS 10

typedef short short8 __attribute__((ext_vector_type(8)));
typedef float floatx4 __attribute__((ext_vector_type(4)));

// fp32 <-> bf16 helpers (RNE)
static __device__ __forceinline__ unsigned short f2bf(float f) {
    unsigned u = __float_as_uint(f);
    u += 0x7FFF + ((u >> 16) & 1);
    return (unsigned short)(u >> 16);
}
static __device__ __forceinline__ float bf2f(unsigned short h) {
    return __uint_as_float(((unsigned)h) << 16);
}

// ---------------- CSR build: count / dinv / scan / fill ----------------

__global__ void count_kernel(const int* __restrict__ dst, int* __restrict__ cnt, int E) {
    int e = blockIdx.x * blockDim.x + threadIdx.x;
    if (e < E) atomicAdd(&cnt[dst[e]], 1);
}

__global__ void dinv_kernel(const int* __restrict__ cnt, float* __restrict__ dinv, int N) {
    int i = blockIdx.x * blockDim.x + threadIdx.x;
    if (i < N) dinv[i] = rsqrtf((float)cnt[i] + 1.0f);   // +1 = self loop
}

__global__ __launch_bounds__(1024) void scan_kernel(const int* __restrict__ cnt,
                                                    int* __restrict__ rowptr, int N, int E) {
    __shared__ int sums[1024];
    const int t = threadIdx.x;
    const int chunk = (N + 1023) / 1024;
    const int beg = t * chunk;
    const int end = min(beg + chunk, N);
    int s = 0;
    for (int i = beg; i < end; i++) s += cnt[i];
    sums[t] = s;
    __syncthreads();
    for (int off = 1; off < 1024; off <<= 1) {
        int v = (t >= off) ? sums[t - off] : 0;
        __syncthreads();
        sums[t] += v;
        __syncthreads();
    }
    int run = (t == 0) ? 0 : sums[t - 1];
    for (int i = beg; i < end; i++) { rowptr[i] = run; run += cnt[i]; }
    if (t == 1023) rowptr[N] = E;
}

__global__ void fill_kernel(const int* __restrict__ src, const int* __restrict__ dst,
                            const int* __restrict__ rowptr, int* __restrict__ cursor,
                            int* __restrict__ srcs, int E) {
    int e = blockIdx.x * blockDim.x + threadIdx.x;
    if (e < E) {
        int d = dst[e];
        int pos = atomicAdd(&cursor[d], 1);
        srcs[rowptr[d] + pos] = src[e];
    }
}

// ---------------- fp32 -> bf16 cast (x -> S0) ----------------

__global__ __launch_bounds__(256) void cast_kernel(const float4* __restrict__ in,
                                                   unsigned short* __restrict__ out, int n4) {
    int i = blockIdx.x * blockDim.x + threadIdx.x;
    if (i < n4) {
        float4 v = in[i];
        unsigned short o[4] = {f2bf(v.x), f2bf(v.y), f2bf(v.z), f2bf(v.w)};
        *(uint2*)(out + (size_t)i * 4) = *(uint2*)o;
    }
}

// ---------------- weight pack: W[256][256] fp32 -> fragment-ordered bf16 ----------------
// Bpack[((kstep*16 + ntile)*64 + lane)*8 + j] = W[kstep*32 + (lane>>4)*8 + j][ntile*16 + (lane&15)]

__global__ __launch_bounds__(256) void packw_kernel(const float* __restrict__ W,
                                                    unsigned short* __restrict__ Bp) {
    int idx = blockIdx.x * blockDim.x + threadIdx.x;   // [0, 8192)
    int kstep = idx >> 10;
    int ntile = (idx >> 6) & 15;
    int lane  = idx & 63;
    int col   = ntile * 16 + (lane & 15);
    int krow  = kstep * 32 + (lane >> 4) * 8;
    unsigned short o[8];
#pragma unroll
    for (int j = 0; j < 8; j++) o[j] = f2bf(W[(size_t)(krow + j) * FDIM + col]);
    *(uint4*)(Bp + (size_t)idx * 8) = *(uint4*)o;
}

// ---------------- bf16 MFMA GEMM: C[M,256] = A[M,256] @ W ----------------
// block = 256 threads = 4 waves; wave w -> 16 rows; BN=128 (8 n-tiles), grid.y = 2.

__global__ __launch_bounds__(256) void mfma_gemm(const unsigned short* __restrict__ A,
                                                 const unsigned short* __restrict__ Bp,
                                                 unsigned short* __restrict__ C, int M) {
    const int wave = threadIdx.x >> 6;
    const int lane = threadIdx.x & 63;
    const int quad = lane >> 4;
    const int m    = lane & 15;
    const int row0 = blockIdx.x * 64 + wave * 16;
    const int ntbase = blockIdx.y * 8;

    const short* arow = (const short*)A + (size_t)(row0 + m) * FDIM + quad * 8;

    floatx4 acc[8];
#pragma unroll
    for (int i = 0; i < 8; i++) acc[i] = (floatx4){0.f, 0.f, 0.f, 0.f};

#pragma unroll
    for (int kstep = 0; kstep < 8; kstep++) {
        short8 a = *(const short8*)(arow + kstep * 32);
#pragma unroll
        for (int nt = 0; nt < 8; nt++) {
            short8 b = *(const short8*)((const short*)Bp +
                         ((size_t)(kstep * 16 + ntbase + nt) * 64 + lane) * 8);
            acc[nt] = __builtin_amdgcn_mfma_f32_16x16x32_bf16(a, b, acc[nt], 0, 0, 0);
        }
    }

    // C/D layout: col = lane&15, row = quad*4 + r
#pragma unroll
    for (int nt = 0; nt < 8; nt++) {
        int col = (ntbase + nt) * 16 + m;
#pragma unroll
        for (int r = 0; r < 4; r++) {
            int row = row0 + quad * 4 + r;
            if (row < M) C[(size_t)row * FDIM + col] = f2bf(acc[nt][r]);
        }
    }
}

// ---------------- fused gather + self-loop + bias + relu (bf16 state) ----------------
// half-wave (32 lanes) per dst node; lane covers 8 feats (16B load).

__global__ __launch_bounds__(256) void gather_kernel(const unsigned short* __restrict__ h,
                                                     const int* __restrict__ rowptr,
                                                     const int* __restrict__ srcs,
                                                     const float* __restrict__ dinv,
                                                     const float* __restrict__ bias,
                                                     unsigned short* __restrict__ out, int N) {
    const int node = blockIdx.x * 8 + (threadIdx.x >> 5);
    const int lane = threadIdx.x & 31;
    if (node >= N) return;
    const float di = dinv[node];

    float acc[8];
    {
        uint4 sv = *(const uint4*)(h + (size_t)node * FDIM + lane * 8);
        const unsigned* u = (const unsigned*)&sv;
#pragma unroll
        for (int i = 0; i < 4; i++) {
            acc[2 * i]     = di * di * __uint_as_float(u[i] << 16);
            acc[2 * i + 1] = di * di * __uint_as_float(u[i] & 0xFFFF0000u);
        }
        float4 b0 = *(const float4*)(bias + lane * 8);
        float4 b1 = *(const float4*)(bias + lane * 8 + 4);
        acc[0] += b0.x; acc[1] += b0.y; acc[2] += b0.z; acc[3] += b0.w;
        acc[4] += b1.x; acc[5] += b1.y; acc[6] += b1.z; acc[7] += b1.w;
    }

    const int beg = rowptr[node];
    const int end = rowptr[node + 1];
    for (int p = beg; p < end; p++) {
        int s = srcs[p];
        float nm = dinv[s] * di;
        uint4 v = *(const uint4*)(h + (size_t)s * FDIM + lane * 8);
        const unsigned* u = (const unsigned*)&v;
#pragma unroll
        for (int i = 0; i < 4; i++) {
            acc[2 * i]     += nm * __uint_as_float(u[i] << 16);
            acc[2 * i + 1] += nm * __uint_as_float(u[i] & 0xFFFF0000u);
        }
    }

    unsigned short o[8];
#pragma unroll
    for (int i = 0; i < 8; i++) o[i] = f2bf(fmaxf(acc[i], 0.0f));
    *(uint4*)(out + (size_t)node * FDIM + lane * 8) = *(uint4*)o;
}

// ---------------- global add pool (bf16 state; batch sorted) ----------------

__global__ __launch_bounds__(256) void pool_kernel(const unsigned short* __restrict__ state,
                                                   const int* __restrict__ batch,
                                                   float* __restrict__ g, int N) {
    int n0 = blockIdx.x * 16;
    int f = threadIdx.x;
    int cur = -1;
    float run = 0.0f;
    for (int i = 0; i < 16; i++) {
        int n = n0 + i;
        if (n >= N) break;
        int b = batch[n];
        if (b != cur) {
            if (cur >= 0) atomicAdd(&g[(size_t)cur * FDIM + f], run);
            cur = b;
            run = 0.0f;
        }
        run += bf2f(state[(size_t)n * FDIM + f]);
    }
    if (cur >= 0) atomicAdd(&g[(size_t)cur * FDIM + f], run);
}

// ---------------- FC1 + relu ----------------

__global__ __launch_bounds__(256) void fc1_kernel(const float* __restrict__ g,
                                                  const float* __restrict__ W,
                                                  const float* __restrict__ b,
                                                  float* __restrict__ out) {
    __shared__ float gs[FDIM];
    int r = blockIdx.x, f = threadIdx.x;
    gs[f] = g[(size_t)r * FDIM + f];
    __syncthreads();
    float acc = b[f];
    for (int k = 0; k < FDIM; k++) acc += gs[k] * W[(size_t)k * FDIM + f];
    out[(size_t)r * FDIM + f] = fmaxf(acc, 0.0f);
}

// ---------------- FC2 + log_softmax ----------------

__global__ __launch_bounds__(64) void fc2_kernel(const float* __restrict__ gh,
                                                 const float* __restrict__ W,
                                                 const float* __restrict__ b,
                                                 float* __restrict__ out) {
    __shared__ float gs[FDIM];
    __shared__ float logits[NCLASS];
    int r = blockIdx.x;
    int t = threadIdx.x;
    for (int k = t; k < FDIM; k += 64) gs[k] = gh[(size_t)r * FDIM + k];
    __syncthreads();
    if (t < NCLASS) {
        float acc = b[t];
        for (int k = 0; k < FDIM; k++) acc += gs[k] * W[(size_t)k * NCLASS + t];
        logits[t] = acc;
    }
    __syncthreads();
    if (t == 0) {
        float mx = logits[0];
        for (int c = 1; c < NCLASS; c++) mx = fmaxf(mx, logits[c]);
        float s = 0.0f;
        for (int c = 0; c < NCLASS; c++) s += expf(logits[c] - mx);
        float lse = mx + logf(s);
        for (int c = 0; c < NCLASS; c++) out[(size_t)r * NCLASS + c] = logits[c] - lse;
    }
}

// ---------------- launcher ----------------

extern "C" void kernel_launch(void* const* d_in, const int* in_sizes, int n_in,
                              void* d_out, int out_size, void* d_ws, size_t ws_size,
                              hipStream_t stream) {
    const float* x     = (const float*)d_in[0];
    const int*   ei    = (const int*)d_in[1];
    const int*   batch = (const int*)d_in[2];
    const float* W0 = (const float*)d_in[3];  const float* b0 = (const float*)d_in[4];
    const float* W1 = (const float*)d_in[5];  const float* b1 = (const float*)d_in[6];
    const float* W2 = (const float*)d_in[7];  const float* b2 = (const float*)d_in[8];
    const float* fc1W = (const float*)d_in[9];  const float* fc1b = (const float*)d_in[10];
    const float* fc2W = (const float*)d_in[11]; const float* fc2b = (const float*)d_in[12];
    float* out = (float*)d_out;

    const int N = in_sizes[0] / FDIM;
    const int E = in_sizes[1] / 2;
    const int* src = ei;
    const int* dst = ei + E;
    const int Mpad = ((N + 63) / 64) * 64;    // padded rows so MFMA tail loads stay in-bounds

    // workspace layout (16B-aligned chunks)
    char* p = (char*)d_ws;
    unsigned short* S0 = (unsigned short*)p; p += (size_t)Mpad * FDIM * 2;  // node state A
    unsigned short* S1 = (unsigned short*)p; p += (size_t)Mpad * FDIM * 2;  // node state B
    unsigned short* H  = (unsigned short*)p; p += (size_t)Mpad * FDIM * 2;  // GEMM out
    unsigned short* Wp0 = (unsigned short*)p; p += (size_t)8192 * 8 * 2;
    unsigned short* Wp1 = (unsigned short*)p; p += (size_t)8192 * 8 * 2;
    unsigned short* Wp2 = (unsigned short*)p; p += (size_t)8192 * 8 * 2;
    float* dinv = (float*)p; p += (size_t)N * 4;
    int*   cnt  = (int*)p;   p += (size_t)N * 4;        // also reused as fill cursor
    int*   rowptr = (int*)p; p += (size_t)(N + 4) * 4;
    int*   srcs = (int*)p;   p += (size_t)E * 4;
    float* g    = (float*)p; p += (size_t)NGRAPH * FDIM * 4;
    float* gh   = (float*)p;

    // ---- CSR build ----
    hipMemsetAsync(cnt, 0, (size_t)N * sizeof(int), stream);
    count_kernel<<<(E + 255) / 256, 256, 0, stream>>>(dst, cnt, E);
    dinv_kernel<<<(N + 255) / 256, 256, 0, stream>>>(cnt, dinv, N);
    scan_kernel<<<1, 1024, 0, stream>>>(cnt, rowptr, N, E);
    hipMemsetAsync(cnt, 0, (size_t)N * sizeof(int), stream);
    fill_kernel<<<(E + 255) / 256, 256, 0, stream>>>(src, dst, rowptr, cnt, srcs, E);

    // ---- casts / weight packs ----
    cast_kernel<<<((N * FDIM / 4) + 255) / 256, 256, 0, stream>>>((const float4*)x, S0, N * FDIM / 4);
    packw_kernel<<<32, 256, 0, stream>>>(W0, Wp0);
    packw_kernel<<<32, 256, 0, stream>>>(W1, Wp1);
    packw_kernel<<<32, 256, 0, stream>>>(W2, Wp2);

    // ---- 3 GCN layers ----
    const unsigned short* Wps[3] = {Wp0, Wp1, Wp2};
    const float* bs[3] = {b0, b1, b2};
    unsigned short* states[4] = {S0, S1, S0, S1};
    dim3 ggrid((N + 63) / 64, 2);
    for (int l = 0; l < 3; l++) {
        mfma_gemm<<<ggrid, 256, 0, stream>>>(states[l], Wps[l], H, N);
        gather_kernel<<<(N + 7) / 8, 256, 0, stream>>>(H, rowptr, srcs, dinv, bs[l],
                                                       states[l + 1], N);
    }

    // ---- head ----
    hipMemsetAsync(g, 0, (size_t)NGRAPH * FDIM * sizeof(float), stream);
    pool_kernel<<<(N + 15) / 16, 256, 0, stream>>>(states[3], batch, g, N);
    fc1_kernel<<<NGRAPH, 256, 0, stream>>>(g, fc1W, fc1b, gh);
    fc2_kernel<<<NGRAPH, 64, 0, stream>>>(gh, fc2W, fc2b, out);
}